// Round 9
// baseline (124.036 us; speedup 1.0000x reference)
//
#include <hip/hip_runtime.h>
#include <stdint.h>

#define NROWS 8192
#define MCOLS 8192
#define DDIM  64
#define NBX   32     // grid.x (col-tile blocks) -> partials per row
#define NBY   64     // grid.y (row-tile blocks) -> partials per col

typedef _Float16 half8   __attribute__((ext_vector_type(8)));
typedef float    floatx4 __attribute__((ext_vector_type(4)));

// ---------- monotone float <-> uint key (for max-reduce argmax) ----------
__device__ __forceinline__ unsigned f2key(float f) {
  unsigned u = __float_as_uint(f);
  return (u & 0x80000000u) ? ~u : (u | 0x80000000u);
}
__device__ __forceinline__ float key2f(unsigned k) {
  unsigned u = (k & 0x80000000u) ? (k & 0x7fffffffu) : ~k;
  return __uint_as_float(u);
}

// ---------- fused: fp16-split conversion + row norms ----------
__global__ void convert_kernel(const float* __restrict__ x, const float* __restrict__ y,
                               _Float16* __restrict__ xh, _Float16* __restrict__ xl,
                               _Float16* __restrict__ yh, _Float16* __restrict__ yl,
                               float* __restrict__ xn, float* __restrict__ yn) {
  __shared__ float lnorm[32];
  const int gid = blockIdx.x * 256 + threadIdx.x;      // 0 .. 131071
  if (threadIdx.x < 32) lnorm[threadIdx.x] = 0.0f;
  __syncthreads();

  const float* src; _Float16 *dh, *dl; float* nout; int t, rowbase;
  if (gid < 65536) { src = x; dh = xh; dl = xl; nout = xn; t = gid;
                     rowbase = blockIdx.x * 32; }
  else             { src = y; dh = yh; dl = yl; nout = yn; t = gid - 65536;
                     rowbase = (blockIdx.x - 256) * 32; }

  const int lane = t & 63;
  const int c    = (t >> 6) & 1;
  const int p    = t >> 7;
  const int row  = p * 16 + (lane & 15);
  const int k0   = c * 32 + ((lane >> 4) << 3);
  const float* s = src + (size_t)row * DDIM + k0;

  float fb[8];
  *(floatx4*)(&fb[0]) = *(const floatx4*)(s);
  *(floatx4*)(&fb[4]) = *(const floatx4*)(s + 4);

  _Float16 hbuf[8], lbuf[8];
  float s8 = 0.0f;
  #pragma unroll
  for (int j = 0; j < 8; ++j) {
    float f = fb[j];
    _Float16 h = (_Float16)f;
    hbuf[j] = h;
    lbuf[j] = (_Float16)((f - (float)h) * 2048.0f);
    s8 = fmaf(f, f, s8);
  }
  size_t o = (size_t)t * 8;
  *(half8*)(dh + o) = *(half8*)hbuf;
  *(half8*)(dl + o) = *(half8*)lbuf;

  atomicAdd(&lnorm[((p & 1) << 4) | (t & 15)], s8);
  __syncthreads();
  if (threadIdx.x < 32) nout[rowbase + threadIdx.x] = lnorm[threadIdx.x];
}

#define MFMA16(A, B, C) __builtin_amdgcn_mfma_f32_16x16x32_f16((A), (B), (C), 0, 0, 0)

// ---------- main pass: block = 4 waves, each wave 32 rows x 256 cols ----------
// Round-9: panel-granularity pipeline.  Instead of {MFMA both panels of jt+1;
// EPILOGUE both panels of jt} (4 result-sets at peak), interleave
// {MFMA(Q,p0); EPI(P,p0); MFMA(Q,p1); EPI(P,p1)} so Pc*a dies mid-step ->
// peak 3 result-sets (-16 unified regs).  Mechanism: occupancy data shows
// VGPR60 kernels get 3 blocks/CU (35.6%), VGPR80 get 2.2 (27%) -- the
// 512-reg unified file's 3-waves/SIMD threshold is ~170 total/wave and we
// sit just above it.  Col-state (cmax/cidx/csum) carries across halves with
// identical comparison order and sum tree -> bit-compatible.
__global__ __launch_bounds__(256, 3) void mfma_tile_kernel(
    const _Float16* __restrict__ xh, const _Float16* __restrict__ xl,
    const _Float16* __restrict__ yh, const _Float16* __restrict__ yl,
    const float* __restrict__ xn, const float* __restrict__ yn,
    unsigned long long* __restrict__ row_part_key, float* __restrict__ row_part_sum,
    unsigned long long* __restrict__ col_part_key, float* __restrict__ col_part_sum)
{
  __shared__ unsigned long long lkey[4][256];   // per-wave col keys (8 KB)
  __shared__ float              lsum[4][256];   // per-wave col sums (4 KB)

  const int wave = threadIdx.x >> 6;
  const int lane = threadIdx.x & 63;
  const int l15  = lane & 15;
  const int g    = lane >> 4;                // row-group 0..3
  const int ap0  = blockIdx.y * 8 + wave * 2;       // first of 2 A panels
  const int ro   = ap0 * 16 + g * 4;                // first row this lane covers
  const int colbase = blockIdx.x * 256;

  #pragma unroll
  for (int w = 0; w < 4; ++w) {
    lkey[w][threadIdx.x] = 0ull;
    lsum[w][threadIdx.x] = 0.0f;
  }
  __syncthreads();

  // ---- A fragments: 2 panels x (2 hi + 2 lo chunks), 32 VGPRs ----
  const half8* xh8 = (const half8*)xh;
  const half8* xl8 = (const half8*)xl;
  const half8* yh8 = (const half8*)yh;
  const half8* yl8 = (const half8*)yl;
  const size_t a0 = (size_t)ap0 * 128 + lane;
  half8 Ah[2][2], Al[2][2];
  #pragma unroll
  for (int p = 0; p < 2; ++p) {
    Ah[p][0] = xh8[a0 + p * 128];      Ah[p][1] = xh8[a0 + p * 128 + 64];
    Al[p][0] = xl8[a0 + p * 128];      Al[p][1] = xl8[a0 + p * 128 + 64];
  }

  // ---- per-row state: 8 rows/lane ----
  float xne[8], rsum[8], rmax[8]; int ridx[8];
  #pragma unroll
  for (int s = 0; s < 8; ++s) {
    xne[s]  = xn[ro + ((s >> 2) << 4) + (s & 3)];
    rsum[s] = 0.0f; rmax[s] = -3.4e38f; ridx[s] = 0;
  }

  const size_t bcol0 = (size_t)(blockIdx.x * 16) * 128 + lane;

  // ---- double-buffered B fragments + column norms ----
  half8 b0h0, b0h1, b0l0, b0l1; float y0n;
  half8 b1h0, b1h1, b1l0, b1l1; float y1n;
  b0h0 = yh8[bcol0];        b0h1 = yh8[bcol0 + 64];
  b0l0 = yl8[bcol0];        b0l1 = yl8[bcol0 + 64];
  y0n  = yn[colbase + l15];
  b1h0 = yh8[bcol0 + 128];  b1h1 = yh8[bcol0 + 192];
  b1l0 = yl8[bcol0 + 128];  b1l1 = yl8[bcol0 + 192];
  y1n  = yn[colbase + 16 + l15];

// one panel's 6 MFMAs (K=64 hi + mixed lo correction)
#define MFMA_PANEL(PIDX, BH0, BH1, BL0, BL1, O1, O2)                           \
  {                                                                            \
    floatx4 c1_ = {}, c2_ = {};                                                \
    c1_ = MFMA16(Ah[PIDX][0], BH0, c1_);                                       \
    c1_ = MFMA16(Ah[PIDX][1], BH1, c1_);                                       \
    c2_ = MFMA16(Al[PIDX][0], BH0, c2_);                                       \
    c2_ = MFMA16(Al[PIDX][1], BH1, c2_);                                       \
    c2_ = MFMA16(Ah[PIDX][0], BL0, c2_);                                       \
    c2_ = MFMA16(Ah[PIDX][1], BL1, c2_);                                       \
    O1 = c1_; O2 = c2_;                                                        \
  }

// epilogue, rows s=0..3 (panel 0): initializes carried col-state
#define EPI_HALF0(JT, C1, C2, YNC, CMAX, CIDX, CSUM)                           \
  {                                                                            \
    const int col_ = colbase + (JT) * 16 + l15;                                \
    float ee_[4];                                                              \
    _Pragma("unroll")                                                          \
    for (int r = 0; r < 4; ++r) {                                              \
      const int s_ = r;                                                        \
      float dot = fmaf(C2[r], (1.0f / 2048.0f), C1[r]);                        \
      float sq  = fmaxf(fmaf(-2.0f, dot, xne[s_] + (YNC)), 0.0f);              \
      float d   = 2.0f - __builtin_amdgcn_sqrtf(sq);                           \
      float e   = __expf(d);                                                   \
      rsum[s_] += e;                                                           \
      if (d > rmax[s_]) ridx[s_] = col_;   /* cols ascend -> first max */      \
      rmax[s_] = fmaxf(rmax[s_], d);                                           \
      if (d > CMAX) CIDX = s_;             /* rows ascend -> first max */      \
      CMAX = fmaxf(CMAX, d);                                                   \
      ee_[r] = e;                                                              \
    }                                                                          \
    CSUM = (ee_[0] + ee_[1]) + (ee_[2] + ee_[3]);                              \
  }

// epilogue, rows s=4..7 (panel 1): finishes col-state, fires LDS atomics
#define EPI_HALF1(JT, C1, C2, YNC, CMAX, CIDX, CSUM)                           \
  {                                                                            \
    const int col_ = colbase + (JT) * 16 + l15;                                \
    float ee_[4];                                                              \
    _Pragma("unroll")                                                          \
    for (int r = 0; r < 4; ++r) {                                              \
      const int s_ = 4 + r;                                                    \
      float dot = fmaf(C2[r], (1.0f / 2048.0f), C1[r]);                        \
      float sq  = fmaxf(fmaf(-2.0f, dot, xne[s_] + (YNC)), 0.0f);              \
      float d   = 2.0f - __builtin_amdgcn_sqrtf(sq);                           \
      float e   = __expf(d);                                                   \
      rsum[s_] += e;                                                           \
      if (d > rmax[s_]) ridx[s_] = col_;                                       \
      rmax[s_] = fmaxf(rmax[s_], d);                                           \
      if (d > CMAX) CIDX = s_;                                                 \
      CMAX = fmaxf(CMAX, d);                                                   \
      ee_[r] = e;                                                              \
    }                                                                          \
    CSUM = CSUM + ((ee_[0] + ee_[1]) + (ee_[2] + ee_[3]));  /* same tree */    \
    int crow_ = ro + ((CIDX >> 2) << 4) + (CIDX & 3);                          \
    unsigned long long ckey_ =                                                 \
        ((unsigned long long)f2key(CMAX) << 32) |                              \
        (unsigned long long)(unsigned)(~(unsigned)crow_);                      \
    atomicMax(&lkey[wave][(JT) * 16 + l15], ckey_);                            \
    atomicAdd(&lsum[wave][(JT) * 16 + l15], CSUM);                             \
  }

  // ---- results pipeline: P = current tile, Q = next tile ----
  floatx4 Pc1a, Pc2a, Pc1b, Pc2b;
  floatx4 Qc1a, Qc2a, Qc1b, Qc2b;

  // prologue: tile 0 into P
  MFMA_PANEL(0, b0h0, b0h1, b0l0, b0l1, Pc1a, Pc2a);
  MFMA_PANEL(1, b0h0, b0h1, b0l0, b0l1, Pc1b, Pc2b);

  for (int jt = 0; jt < 14; jt += 2) {
    // even step: MFMA tile jt+1 (buf1) interleaved with epilogue tile jt (P);
    // prefetch jt+2 -> buf0
    {
      float ycur = y0n;
      const size_t bn = bcol0 + (size_t)(jt + 2) * 128;
      b0h0 = yh8[bn];      b0h1 = yh8[bn + 64];
      b0l0 = yl8[bn];      b0l1 = yl8[bn + 64];
      y0n  = yn[colbase + (jt + 2) * 16 + l15];
      float cmax_ = -3.4e38f; int cidx_ = 0; float csum_;
      MFMA_PANEL(0, b1h0, b1h1, b1l0, b1l1, Qc1a, Qc2a);
      EPI_HALF0(jt, Pc1a, Pc2a, ycur, cmax_, cidx_, csum_);
      MFMA_PANEL(1, b1h0, b1h1, b1l0, b1l1, Qc1b, Qc2b);
      EPI_HALF1(jt, Pc1b, Pc2b, ycur, cmax_, cidx_, csum_);
    }
    // odd step: MFMA tile jt+2 (buf0) interleaved with epilogue tile jt+1 (Q);
    // prefetch jt+3 -> buf1
    {
      float ycur = y1n;
      const size_t bn = bcol0 + (size_t)(jt + 3) * 128;
      b1h0 = yh8[bn];      b1h1 = yh8[bn + 64];
      b1l0 = yl8[bn];      b1l1 = yl8[bn + 64];
      y1n  = yn[colbase + (jt + 3) * 16 + l15];
      float cmax_ = -3.4e38f; int cidx_ = 0; float csum_;
      MFMA_PANEL(0, b0h0, b0h1, b0l0, b0l1, Pc1a, Pc2a);
      EPI_HALF0(jt + 1, Qc1a, Qc2a, ycur, cmax_, cidx_, csum_);
      MFMA_PANEL(1, b0h0, b0h1, b0l0, b0l1, Pc1b, Pc2b);
      EPI_HALF1(jt + 1, Qc1b, Qc2b, ycur, cmax_, cidx_, csum_);
    }
  }
  // step 14: MFMA tile 15 (buf1) interleaved with epilogue tile 14 (P)
  {
    float cmax_ = -3.4e38f; int cidx_ = 0; float csum_;
    MFMA_PANEL(0, b1h0, b1h1, b1l0, b1l1, Qc1a, Qc2a);
    EPI_HALF0(14, Pc1a, Pc2a, y0n, cmax_, cidx_, csum_);
    MFMA_PANEL(1, b1h0, b1h1, b1l0, b1l1, Qc1b, Qc2b);
    EPI_HALF1(14, Pc1b, Pc2b, y0n, cmax_, cidx_, csum_);
  }
  // step 15: epilogue tile 15 (Q) only
  {
    float cmax_ = -3.4e38f; int cidx_ = 0; float csum_;
    EPI_HALF0(15, Qc1a, Qc2a, y1n, cmax_, cidx_, csum_);
    EPI_HALF1(15, Qc1b, Qc2b, y1n, cmax_, cidx_, csum_);
  }

#undef MFMA_PANEL
#undef EPI_HALF0
#undef EPI_HALF1

  // ---- row reduce: one butterfly over the 16 lane-columns, once per kernel ----
  unsigned long long rkk[8];
  #pragma unroll
  for (int s = 0; s < 8; ++s)
    rkk[s] = ((unsigned long long)f2key(rmax[s]) << 32) |
             (unsigned long long)(unsigned)(~(unsigned)ridx[s]);
  #pragma unroll
  for (int off = 1; off < 16; off <<= 1) {
    #pragma unroll
    for (int s = 0; s < 8; ++s) {
      rsum[s] += __shfl_xor(rsum[s], off);
      unsigned long long o = __shfl_xor(rkk[s], off);
      if (o > rkk[s]) rkk[s] = o;
    }
  }
  if (l15 == 0) {
    #pragma unroll
    for (int s = 0; s < 8; ++s) {
      int row = ro + ((s >> 2) << 4) + (s & 3);
      row_part_key[(size_t)blockIdx.x * NROWS + row] = rkk[s];
      row_part_sum[(size_t)blockIdx.x * NROWS + row] = rsum[s];
    }
  }

  // ---- block-level col flush: merge the 4 per-wave banks, plain stores ----
  __syncthreads();
  {
    int col = colbase + threadIdx.x;
    unsigned long long k0 = lkey[0][threadIdx.x], k1 = lkey[1][threadIdx.x];
    unsigned long long k2 = lkey[2][threadIdx.x], k3 = lkey[3][threadIdx.x];
    unsigned long long ka = k0 > k1 ? k0 : k1;
    unsigned long long kb = k2 > k3 ? k2 : k3;
    col_part_key[(size_t)blockIdx.y * MCOLS + col] = ka > kb ? ka : kb;
    col_part_sum[(size_t)blockIdx.y * MCOLS + col] =
        (lsum[0][threadIdx.x] + lsum[1][threadIdx.x]) +
        (lsum[2][threadIdx.x] + lsum[3][threadIdx.x]);
  }
}

// ---------- finalize: col partials + inline row reduction + mutual test -----
__global__ __launch_bounds__(256) void finalize_kernel(
    const unsigned long long* __restrict__ rpk,
    const float* __restrict__ rps,
    const unsigned long long* __restrict__ cpk,
    const float* __restrict__ cps,
    float* __restrict__ out)
{
  const int t = blockIdx.x * 256 + threadIdx.x;     // 0 .. 65535
  const int j = t >> 3;
  const int i = t & 7;

  unsigned long long ck = 0ull; float csum = 0.0f;
  #pragma unroll
  for (int k = 0; k < 8; ++k) {
    const int by = i + k * 8;
    unsigned long long kk = cpk[(size_t)by * MCOLS + j];
    if (kk > ck) ck = kk;
    csum += cps[(size_t)by * MCOLS + j];
  }
  #pragma unroll
  for (int off = 1; off < 8; off <<= 1) {
    csum += __shfl_xor(csum, off);
    unsigned long long o = __shfl_xor(ck, off);
    if (o > ck) ck = o;
  }

  const int ci = (int)(~(unsigned)ck);              // same in all 8 lanes

  unsigned long long rk = 0ull; float rsum = 0.0f;
  #pragma unroll
  for (int k = 0; k < 4; ++k) {
    const int bx = i + k * 8;
    unsigned long long kk = rpk[(size_t)bx * NROWS + ci];
    if (kk > rk) rk = kk;
    rsum += rps[(size_t)bx * NROWS + ci];
  }
  #pragma unroll
  for (int off = 1; off < 8; off <<= 1) {
    rsum += __shfl_xor(rsum, off);
    unsigned long long o = __shfl_xor(rk, off);
    if (o > rk) rk = o;
  }
  if (i != 0) return;

  float cmax = key2f((unsigned)(ck >> 32));
  float lp_col = cmax - logf(csum);

  int   rj   = (int)(~(unsigned)rk);
  float rmax = key2f((unsigned)(rk >> 32));
  float lp_row = rmax - logf(rsum);

  int mut = (rj == j);
  out[j]                 = mut ? (lp_row + lp_col) : 0.0f;
  out[MCOLS + 2 * j + 0] = (float)ci;
  out[MCOLS + 2 * j + 1] = (float)j;
  out[3 * MCOLS + j]     = mut ? 1.0f : 0.0f;
}

extern "C" void kernel_launch(void* const* d_in, const int* in_sizes, int n_in,
                              void* d_out, int out_size, void* d_ws, size_t ws_size,
                              hipStream_t stream) {
  const float* x = (const float*)d_in[0];
  const float* y = (const float*)d_in[1];
  float* out = (float*)d_out;

  char* ws = (char*)d_ws;
  // layout (bytes):
  float* xn      = (float*)(ws);                                        //   0      32 KB
  float* yn      = (float*)(ws + 32768);                                //  32K     32 KB
  unsigned long long* rpk = (unsigned long long*)(ws + 65536);          //  64K      2 MB
  float* rps     = (float*)(ws + 2162688);                              //           1 MB
  unsigned long long* cpk = (unsigned long long*)(ws + 3211264);        //           4 MB
  float* cps     = (float*)(ws + 7405568);                              //           2 MB
  _Float16* xh = (_Float16*)(ws + 9502720);                             //           1 MB
  _Float16* xl = (_Float16*)(ws + 10551296);                            //           1 MB
  _Float16* yh = (_Float16*)(ws + 11599872);                            //           1 MB
  _Float16* yl = (_Float16*)(ws + 12648448);                            //           1 MB
                                                                        // end ~13.1 MB

  convert_kernel<<<512, 256, 0, stream>>>(x, y, xh, xl, yh, yl, xn, yn);
  dim3 grid(MCOLS / 256, NROWS / 128);     // 32 x 64 blocks, 256 threads
  mfma_tile_kernel<<<grid, 256, 0, stream>>>(xh, xl, yh, yl, xn, yn,
                                             rpk, rps, cpk, cps);
  finalize_kernel<<<256, 256, 0, stream>>>(rpk, rps, cpk, cps, out);
}